// Round 9
// baseline (156.359 us; speedup 1.0000x reference)
//
#include <hip/hip_runtime.h>
#include <stdint.h>

#define BB 4
#define NN 2000
#define K_PRE 1000
#define KPAD 1024
#define MAXOUT 128
#define NMS_THR 0.3f
#define MASK_IN_VOX (28*28*28)   // 21952
#define MASK_OUT_VOX (32*32*32)  // 32768
#define STAGE_ROWS 496
#define K1_LDS (STAGE_ROWS * 64 * 2)   // 63488 B dynamic (< 64 KB default cap)
#define CELLS_PER_BAR 160              // uint32s per barrier (8 groups*16 + root@128 + release@144)

// ---------------- hierarchical agent-scope grid barrier ---------------------
// 256 co-resident blocks (grid=256, 1/CU; co-residency + acq/rel chain proven R7).
// 8 arrival cells 64 B apart (blk&7 ~ XCD under round-robin dispatch): 32
// same-XCD RMWs each, in parallel across groups; 8 cross-XCD root RMWs; one
// release store. Transitive sync chain makes all pre-barrier writes visible.
__device__ __forceinline__ void grid_barrier(uint32_t* base, int blk, int tid) {
    __syncthreads();
    if (tid == 0) {
        int g = blk & 7;
        uint32_t a = __hip_atomic_fetch_add(base + g * 16, 1u,
                                            __ATOMIC_ACQ_REL, __HIP_MEMORY_SCOPE_AGENT);
        if (a == 31u) {
            uint32_t r = __hip_atomic_fetch_add(base + 8 * 16, 1u,
                                                __ATOMIC_ACQ_REL, __HIP_MEMORY_SCOPE_AGENT);
            if (r == 7u)
                __hip_atomic_store(base + 9 * 16, 1u,
                                   __ATOMIC_RELEASE, __HIP_MEMORY_SCOPE_AGENT);
        }
        while (__hip_atomic_load(base + 9 * 16, __ATOMIC_ACQUIRE,
                                 __HIP_MEMORY_SCOPE_AGENT) == 0u)
            __builtin_amdgcn_s_sleep(8);
    }
    __syncthreads();
}

// ---------------- phase bodies (R4/R7-proven) --------------------------------

__device__ __forceinline__ void dev_rank(int b, int chunk, int tid, float* s,
                                         const float* __restrict__ scores,
                                         const float* __restrict__ proposals,
                                         const float* __restrict__ deltas,
                                         int* __restrict__ order,
                                         float* __restrict__ boxes_ws) {
    const float* sb = scores + b * NN;
    for (int u = tid; u < NN / 4; u += 256)
        ((float4*)s)[u] = ((const float4*)sb)[u];
    __syncthreads();

    int i = chunk * 64 + (tid >> 2);
    int q = tid & 3;
    float si = (i < NN) ? s[i] : 0.f;
    int cnt = 0;
    int j0 = q * 500;
    const float4* s4 = (const float4*)s;
#pragma unroll 5
    for (int u = 0; u < 125; ++u) {
        float4 v = s4[j0 / 4 + u];
        int j = j0 + u * 4;
        cnt += (v.x > si) + (v.y > si) + (v.z > si) + (v.w > si);
        cnt += ((v.x == si) & (j + 0 < i)) + ((v.y == si) & (j + 1 < i))
             + ((v.z == si) & (j + 2 < i)) + ((v.w == si) & (j + 3 < i));
    }
    cnt += __shfl_xor(cnt, 1);
    cnt += __shfl_xor(cnt, 2);

    if (q == 0 && i < NN && cnt < K_PRE) {
        int rank = cnt;
        order[b * KPAD + rank] = i;
        const float* p = proposals + (size_t)(b * NN + i) * 6;
        const float* d = deltas    + (size_t)(b * NN + i) * 6;
        float py1 = p[0], px1 = p[1], pz1 = p[2], py2 = p[3], px2 = p[4], pz2 = p[5];
        float h = py2 - py1, w = px2 - px1, dd = pz2 - pz1;
        float cy = py1 + 0.5f * h + d[0] * h;
        float cx = px1 + 0.5f * w + d[1] * w;
        float cz = pz1 + 0.5f * dd + d[2] * dd;
        h *= expf(d[3]); w *= expf(d[4]); dd *= expf(d[5]);
        float* bw = boxes_ws + (size_t)b * 6 * KPAD + rank;
        bw[0 * KPAD] = cy - 0.5f * h;  bw[1 * KPAD] = cx - 0.5f * w;  bw[2 * KPAD] = cz - 0.5f * dd;
        bw[3 * KPAD] = cy + 0.5f * h;  bw[4 * KPAD] = cx + 0.5f * w;  bw[5 * KPAD] = cz + 0.5f * dd;
    }
}

// rowBits[(b*KPAD+k)*64+l] (uint16): bit w <=> IoU(box k, box 64w+l) > thr.
// Pad rows k>=1000 are NOT written (their bytes are reused as barrier cells,
// and they are never read: pads are pre-suppressed so never selected/prefetched).
__device__ __forceinline__ void dev_build(int b, int kbase, int tid, float (*sbx)[1088],
                                          const float* __restrict__ boxes_ws,
                                          unsigned short* __restrict__ rowBits) {
    const float* bw = boxes_ws + (size_t)b * 6 * KPAD;
    for (int k = tid; k < KPAD; k += 256) {
        int ks = k + (k >> 4);
#pragma unroll
        for (int c = 0; c < 6; ++c) sbx[c][ks] = bw[c * KPAD + k];
    }
    __syncthreads();
    int l = tid & 63, lr = tid >> 6;
#pragma unroll
    for (int pss = 0; pss < 4; ++pss) {
        int k = kbase + pss * 4 + lr;
        int ks = k + (k >> 4);
        float ry1 = sbx[0][ks], rx1 = sbx[1][ks], rz1 = sbx[2][ks];
        float ry2 = sbx[3][ks], rx2 = sbx[4][ks], rz2 = sbx[5][ks];
        float v1 = (ry2 - ry1) * (rx2 - rx1) * (rz2 - rz1);
        uint32_t bits = 0;
#pragma unroll
        for (int w = 0; w < 16; ++w) {
            int j = 64 * w + l;
            int js = j + (j >> 4);
            float y1 = sbx[0][js], x1 = sbx[1][js], z1 = sbx[2][js];
            float y2 = sbx[3][js], x2 = sbx[4][js], z2 = sbx[5][js];
            float iy = fmaxf(fminf(ry2, y2) - fmaxf(ry1, y1), 0.f);
            float ix = fmaxf(fminf(rx2, x2) - fmaxf(rx1, x1), 0.f);
            float iz = fmaxf(fminf(rz2, z2) - fmaxf(rz1, z1), 0.f);
            float inter = iy * ix * iz;
            float v2 = (y2 - y1) * (x2 - x1) * (z2 - z1);
            float iou = inter / (v1 + v2 - inter + 1e-8f);
            bits |= (iou > NMS_THR ? 1u : 0u) << w;
        }
        if (k < K_PRE)
            rowBits[((size_t)(b * KPAD + k)) * 64 + l] = (unsigned short)bits;
    }
}

// ballot walk with depth-4 candidate prefetch; rows [0,STAGE_ROWS) from LDS
__device__ __forceinline__ void dev_walk(int b, int tid, unsigned short* rows_lds,
                                         const unsigned short* __restrict__ rowBits,
                                         const int* __restrict__ order,
                                         const float* __restrict__ boxes_ws,
                                         float* __restrict__ out_boxes,
                                         float* __restrict__ out_bidx,
                                         int* __restrict__ g_idx,
                                         float* __restrict__ g_valid) {
    __shared__ short sel_k[MAXOUT];
    const unsigned short* rowB = rowBits + (size_t)b * KPAD * 64;
    const uint4* src4 = (const uint4*)rowB;
    uint4* dst4 = (uint4*)rows_lds;
    for (int t = tid; t < STAGE_ROWS * 64 * 2 / 16; t += 256) dst4[t] = src4[t];
    __syncthreads();
    if (tid < 64) {
        int lane = tid;
        uint32_t sup = (lane >= 40) ? (1u << 15) : 0u;   // pads >=1000 pre-suppressed
        int nsel = 0;

        auto ROW = [&](int g) -> unsigned short {
            return (g < STAGE_ROWS) ? rows_lds[(g << 6) + lane]
                                    : rowB[((size_t)g << 6) + lane];
        };

        for (int w = 0; w < 16 && nsel < MAXOUT; ++w) {
            unsigned long long m = ~__ballot((int)((sup >> w) & 1u));
            while (m != 0ull && nsel < MAXOUT) {
                unsigned long long t = m;
                int k1 = __builtin_ctzll(t); t &= t - 1;
                bool h2 = t != 0; int k2 = h2 ? __builtin_ctzll(t) : k1; t &= t - 1;
                bool h3 = t != 0; int k3 = h3 ? __builtin_ctzll(t) : k1; t &= t - 1;
                bool h4 = t != 0; int k4 = h4 ? __builtin_ctzll(t) : k1;
                int g1 = (w << 6) + k1, g2 = (w << 6) + k2;
                int g3 = (w << 6) + k3, g4 = (w << 6) + k4;
                unsigned short r1 = ROW(g1), r2 = ROW(g2), r3 = ROW(g3), r4 = ROW(g4);
                sup |= r1; if (lane == 0) sel_k[nsel] = (short)g1; nsel++;
                m = ~__ballot((int)((sup >> w) & 1u));
                if (h2 && nsel < MAXOUT && ((m >> k2) & 1ull)) {
                    sup |= r2; if (lane == 0) sel_k[nsel] = (short)g2; nsel++;
                    m = ~__ballot((int)((sup >> w) & 1u));
                }
                if (h3 && nsel < MAXOUT && ((m >> k3) & 1ull)) {
                    sup |= r3; if (lane == 0) sel_k[nsel] = (short)g3; nsel++;
                    m = ~__ballot((int)((sup >> w) & 1u));
                }
                if (h4 && nsel < MAXOUT && ((m >> k4) & 1ull)) {
                    sup |= r4; if (lane == 0) sel_k[nsel] = (short)g4; nsel++;
                    m = ~__ballot((int)((sup >> w) & 1u));
                }
            }
        }
        __builtin_amdgcn_s_waitcnt(0);
        const float* bw = boxes_ws + (size_t)b * 6 * KPAD;
#pragma unroll
        for (int s0 = 0; s0 < 2; ++s0) {
            int s = lane + s0 * 64;
            int valid = s < nsel;
            int k = valid ? (int)sel_k[s] : 0;
            int idx = valid ? order[b * KPAD + k] : 0;
            float vf = valid ? 1.f : 0.f;
            g_idx[b * MAXOUT + s] = idx;
            g_valid[b * MAXOUT + s] = vf;
            float* ob = out_boxes + (size_t)(b * MAXOUT + s) * 6;
#pragma unroll
            for (int c = 0; c < 6; ++c) ob[c] = bw[c * KPAD + k] * vf;
            out_bidx[b * MAXOUT + s] = (float)b;
        }
    }
}

__device__ __forceinline__ void dev_resize(int s, int tid, float* rowbuf,
                                           const float* __restrict__ masks,
                                           const int* __restrict__ g_idx,
                                           const float* __restrict__ g_valid,
                                           float* __restrict__ out_masks) {
    int b = s >> 7;
    int gi = g_idx[s];
    float vf = g_valid[s];
    const float* src = masks + (size_t)(b * NN + gi) * MASK_IN_VOX;
    float* dst = out_masks + (size_t)s * MASK_OUT_VOX;
    int lane = tid & 63;
    float* rb = rowbuf + (tid >> 6) * (64 * 36);
    const float4* s4b = (const float4*)src;

#pragma unroll
    for (int p = 0; p < 4; ++p) {
        int idx = p * 256 + tid;
        int oy = idx & 31, oz = idx >> 5;

        float syf = 0.875f * oy - 0.0625f;
        int fly = (syf >= 0.f) ? (int)syf : -1;
        float fy = syf - (float)fly;
        int y0 = fly < 0 ? 0 : fly;
        int y1 = fly + 1 > 27 ? 27 : fly + 1;

        float szf = 0.875f * oz - 0.0625f;
        int flz = (szf >= 0.f) ? (int)szf : -1;
        float fz = szf - (float)flz;
        int z0 = flz < 0 ? 0 : flz;
        int z1 = flz + 1 > 27 ? 27 : flz + 1;

        float w00 = (1.f - fy) * (1.f - fz);
        float w01 = fy * (1.f - fz);
        float w10 = (1.f - fy) * fz;
        float w11 = fy * fz;

        const float4* r00 = s4b + (z0 * 28 + y0) * 7;
        const float4* r01 = s4b + (z0 * 28 + y1) * 7;
        const float4* r10 = s4b + (z1 * 28 + y0) * 7;
        const float4* r11 = s4b + (z1 * 28 + y1) * 7;

        float c[28];
#pragma unroll
        for (int t = 0; t < 7; ++t) {
            float4 a = r00[t], bb = r01[t], cc = r10[t], dd = r11[t];
            c[4 * t + 0] = a.x * w00 + bb.x * w01 + cc.x * w10 + dd.x * w11;
            c[4 * t + 1] = a.y * w00 + bb.y * w01 + cc.y * w10 + dd.y * w11;
            c[4 * t + 2] = a.z * w00 + bb.z * w01 + cc.z * w10 + dd.z * w11;
            c[4 * t + 3] = a.w * w00 + bb.w * w01 + cc.w * w10 + dd.w * w11;
        }

#pragma unroll
        for (int e = 0; e < 8; ++e) {
            float4 o;
#pragma unroll
            for (int qq = 0; qq < 4; ++qq) {
                const int ox = e * 4 + qq;
                const float sx = 0.875f * (float)ox - 0.0625f;
                const int flx = (ox == 0) ? -1 : (14 * ox - 1) / 16;
                const float fx = sx - (float)flx;
                const int x0 = flx < 0 ? 0 : flx;
                const int x1 = flx + 1 > 27 ? 27 : flx + 1;
                (&o.x)[qq] = (c[x0] + fx * (c[x1] - c[x0])) * vf;
            }
            *(float4*)&rb[lane * 36 + e * 4] = o;
        }

        float4* dchunk = (float4*)dst + (size_t)(p * 256 + (tid & ~63)) * 8;
#pragma unroll
        for (int t = 0; t < 8; ++t) {
            int f = t * 64 + lane;
            float4 v = *(const float4*)&rb[(f >> 3) * 36 + (f & 7) * 4];
            dchunk[f] = v;
        }
    }
}

// ---------------- single fused kernel ----------------------------------------
__global__ __launch_bounds__(256, 1) void detect_kernel(
        const float* __restrict__ scores, const float* __restrict__ proposals,
        const float* __restrict__ deltas, const float* __restrict__ masks,
        int* __restrict__ order, float* __restrict__ boxes_ws,
        unsigned short* __restrict__ rowBits,
        int* __restrict__ g_idx, float* __restrict__ g_valid,
        float* __restrict__ out_boxes, float* __restrict__ out_masks,
        float* __restrict__ out_bidx,
        uint32_t* __restrict__ cells) {
    extern __shared__ __align__(16) char smem[];
    int blk = blockIdx.x;
    int tid = threadIdx.x;

    if (blk < 128)
        dev_rank(blk >> 5, blk & 31, tid, (float*)smem, scores, proposals, deltas,
                 order, boxes_ws);
    grid_barrier(cells + 0 * CELLS_PER_BAR, blk, tid);

    // XCD-swizzled build: batch b's rows 0..511 built on XCD b (walk block b local)
    {
        int xcd = blk & 7;
        int batch = xcd & 3;
        int kbase = (((xcd >> 2) << 5) + (blk >> 3)) << 4;
        dev_build(batch, kbase, tid, (float(*)[1088])smem, boxes_ws, rowBits);
    }
    grid_barrier(cells + 1 * CELLS_PER_BAR, blk, tid);

    if (blk < BB)
        dev_walk(blk, tid, (unsigned short*)smem, rowBits, order, boxes_ws,
                 out_boxes, out_bidx, g_idx, g_valid);
    grid_barrier(cells + 2 * CELLS_PER_BAR, blk, tid);

    for (int r = 0; r < 2; ++r)
        dev_resize(blk * 2 + r, tid, (float*)smem, masks, g_idx, g_valid, out_masks);
}

// ---------------- launch ----------------------------------------------------
extern "C" void kernel_launch(void* const* d_in, const int* in_sizes, int n_in,
                              void* d_out, int out_size, void* d_ws, size_t ws_size,
                              hipStream_t stream) {
    const float* proposals = (const float*)d_in[0];
    const float* scores    = (const float*)d_in[1];
    const float* deltas    = (const float*)d_in[2];
    const float* masks     = (const float*)d_in[3];

    float* out = (float*)d_out;
    float* out_boxes = out;                                              // [512,6]
    float* out_masks = out + (size_t)BB * MAXOUT * 6;                    // [512,32768]
    float* out_bidx  = out + (size_t)BB * MAXOUT * 6 + (size_t)BB * MAXOUT * MASK_OUT_VOX;

    char* ws = (char*)d_ws;
    int*            order    = (int*)(ws);                               // 16 KB
    int*            g_idx    = (int*)(ws + (16 << 10));                  // 2 KB
    float*          g_valid  = (float*)(ws + (18 << 10));                // 2 KB
    float*          boxes_ws = (float*)(ws + (20 << 10));                // 96 KB
    unsigned short* rowBits  = (unsigned short*)(ws + (116 << 10));      // 512 KB -> ends 628 KB
    // barrier cells: inside rowBits, batch 3 pad rows 1000..1023 (3072 B region,
    // never written by build thanks to the k<K_PRE guard, never read by walk
    // because pads are pre-suppressed). 3 barriers x 640 B = 1920 B used.
    uint32_t*       cells    = (uint32_t*)((char*)rowBits
                                           + (size_t)(3 * KPAD + K_PRE) * 64 * 2);

    hipMemsetAsync(cells, 0, 3 * CELLS_PER_BAR * sizeof(uint32_t), stream);

    detect_kernel<<<256, 256, K1_LDS, stream>>>(scores, proposals, deltas, masks,
                                                order, boxes_ws, rowBits,
                                                g_idx, g_valid,
                                                out_boxes, out_masks, out_bidx,
                                                cells);
}

// Round 10
// 89.336 us; speedup vs baseline: 1.7502x; 1.7502x over previous
//
#include <hip/hip_runtime.h>
#include <stdint.h>

#define BB 4
#define NN 2000
#define K_PRE 1000
#define KPAD 1024
#define MAXOUT 128
#define NMS_THR 0.3f
#define MASK_IN_VOX (28*28*28)   // 21952
#define MASK_OUT_VOX (32*32*32)  // 32768
#define STAGE_ROWS 496
#define DYN_LDS (STAGE_ROWS * 64 * 2)   // 63488 B; all phase buffers alias here

// ---------------- dataflow sync primitives (agent scope) --------------------
// arrive: RELEASE RMW only (writes back producer's L2, no invalidate).
// wait:   RELAXED polls (coherent LLC read, NO per-iteration invalidate),
//         then ONE ACQUIRE load (single L2 invalidate) before consuming.
__device__ __forceinline__ void arrive(uint32_t* c) {
    __syncthreads();
    if (threadIdx.x == 0)
        __hip_atomic_fetch_add(c, 1u, __ATOMIC_RELEASE, __HIP_MEMORY_SCOPE_AGENT);
}

__device__ __forceinline__ void wait_for(uint32_t* c, uint32_t target) {
    if (threadIdx.x == 0) {
        int it = 0;
        while (__hip_atomic_load(c, __ATOMIC_RELAXED, __HIP_MEMORY_SCOPE_AGENT) < target) {
            __builtin_amdgcn_s_sleep(2);
            if (++it > (1 << 26)) break;   // safety bound (~seconds); never hit normally
        }
        (void)__hip_atomic_load(c, __ATOMIC_ACQUIRE, __HIP_MEMORY_SCOPE_AGENT);
    }
    __syncthreads();
}

// ---------------- phase bodies (R4/R9-proven, unchanged) ---------------------

__device__ __forceinline__ void dev_rank(int b, int chunk, int tid, float* s,
                                         const float* __restrict__ scores,
                                         const float* __restrict__ proposals,
                                         const float* __restrict__ deltas,
                                         int* __restrict__ order,
                                         float* __restrict__ boxes_ws) {
    const float* sb = scores + b * NN;
    for (int u = tid; u < NN / 4; u += 256)
        ((float4*)s)[u] = ((const float4*)sb)[u];
    __syncthreads();

    int i = chunk * 64 + (tid >> 2);
    int q = tid & 3;
    float si = (i < NN) ? s[i] : 0.f;
    int cnt = 0;
    int j0 = q * 500;
    const float4* s4 = (const float4*)s;
#pragma unroll 5
    for (int u = 0; u < 125; ++u) {
        float4 v = s4[j0 / 4 + u];
        int j = j0 + u * 4;
        cnt += (v.x > si) + (v.y > si) + (v.z > si) + (v.w > si);
        cnt += ((v.x == si) & (j + 0 < i)) + ((v.y == si) & (j + 1 < i))
             + ((v.z == si) & (j + 2 < i)) + ((v.w == si) & (j + 3 < i));
    }
    cnt += __shfl_xor(cnt, 1);
    cnt += __shfl_xor(cnt, 2);

    if (q == 0 && i < NN && cnt < K_PRE) {
        int rank = cnt;
        order[b * KPAD + rank] = i;
        const float* p = proposals + (size_t)(b * NN + i) * 6;
        const float* d = deltas    + (size_t)(b * NN + i) * 6;
        float py1 = p[0], px1 = p[1], pz1 = p[2], py2 = p[3], px2 = p[4], pz2 = p[5];
        float h = py2 - py1, w = px2 - px1, dd = pz2 - pz1;
        float cy = py1 + 0.5f * h + d[0] * h;
        float cx = px1 + 0.5f * w + d[1] * w;
        float cz = pz1 + 0.5f * dd + d[2] * dd;
        h *= expf(d[3]); w *= expf(d[4]); dd *= expf(d[5]);
        float* bw = boxes_ws + (size_t)b * 6 * KPAD + rank;
        bw[0 * KPAD] = cy - 0.5f * h;  bw[1 * KPAD] = cx - 0.5f * w;  bw[2 * KPAD] = cz - 0.5f * dd;
        bw[3 * KPAD] = cy + 0.5f * h;  bw[4 * KPAD] = cx + 0.5f * w;  bw[5 * KPAD] = cz + 0.5f * dd;
    }
}

// rowBits[(b*KPAD+k)*64+l] (uint16): bit w <=> IoU(box k, box 64w+l) > thr.
// 8 rows per block (512 blocks). Pad rows k>=1000 never written (k<K_PRE guard;
// their bytes hold the sync counters) and never read (pads pre-suppressed).
__device__ __forceinline__ void dev_build(int b, int kbase, int tid, float (*sbx)[1088],
                                          const float* __restrict__ boxes_ws,
                                          unsigned short* __restrict__ rowBits) {
    const float* bw = boxes_ws + (size_t)b * 6 * KPAD;
    for (int k = tid; k < KPAD; k += 256) {
        int ks = k + (k >> 4);
#pragma unroll
        for (int c = 0; c < 6; ++c) sbx[c][ks] = bw[c * KPAD + k];
    }
    __syncthreads();
    int l = tid & 63, lr = tid >> 6;
#pragma unroll
    for (int pss = 0; pss < 2; ++pss) {
        int k = kbase + pss * 4 + lr;
        int ks = k + (k >> 4);
        float ry1 = sbx[0][ks], rx1 = sbx[1][ks], rz1 = sbx[2][ks];
        float ry2 = sbx[3][ks], rx2 = sbx[4][ks], rz2 = sbx[5][ks];
        float v1 = (ry2 - ry1) * (rx2 - rx1) * (rz2 - rz1);
        uint32_t bits = 0;
#pragma unroll
        for (int w = 0; w < 16; ++w) {
            int j = 64 * w + l;
            int js = j + (j >> 4);
            float y1 = sbx[0][js], x1 = sbx[1][js], z1 = sbx[2][js];
            float y2 = sbx[3][js], x2 = sbx[4][js], z2 = sbx[5][js];
            float iy = fmaxf(fminf(ry2, y2) - fmaxf(ry1, y1), 0.f);
            float ix = fmaxf(fminf(rx2, x2) - fmaxf(rx1, x1), 0.f);
            float iz = fmaxf(fminf(rz2, z2) - fmaxf(rz1, z1), 0.f);
            float inter = iy * ix * iz;
            float v2 = (y2 - y1) * (x2 - x1) * (z2 - z1);
            float iou = inter / (v1 + v2 - inter + 1e-8f);
            bits |= (iou > NMS_THR ? 1u : 0u) << w;
        }
        if (k < K_PRE)
            rowBits[((size_t)(b * KPAD + k)) * 64 + l] = (unsigned short)bits;
    }
}

// ballot walk with depth-4 candidate prefetch; rows [0,STAGE_ROWS) from LDS
__device__ __forceinline__ void dev_walk(int b, int tid, unsigned short* rows_lds,
                                         const unsigned short* __restrict__ rowBits,
                                         const int* __restrict__ order,
                                         const float* __restrict__ boxes_ws,
                                         float* __restrict__ out_boxes,
                                         float* __restrict__ out_bidx,
                                         int* __restrict__ g_idx,
                                         float* __restrict__ g_valid) {
    __shared__ short sel_k[MAXOUT];
    const unsigned short* rowB = rowBits + (size_t)b * KPAD * 64;
    const uint4* src4 = (const uint4*)rowB;
    uint4* dst4 = (uint4*)rows_lds;
    for (int t = tid; t < STAGE_ROWS * 64 * 2 / 16; t += 256) dst4[t] = src4[t];
    __syncthreads();
    if (tid < 64) {
        int lane = tid;
        uint32_t sup = (lane >= 40) ? (1u << 15) : 0u;   // pads >=1000 pre-suppressed
        int nsel = 0;

        auto ROW = [&](int g) -> unsigned short {
            return (g < STAGE_ROWS) ? rows_lds[(g << 6) + lane]
                                    : rowB[((size_t)g << 6) + lane];
        };

        for (int w = 0; w < 16 && nsel < MAXOUT; ++w) {
            unsigned long long m = ~__ballot((int)((sup >> w) & 1u));
            while (m != 0ull && nsel < MAXOUT) {
                unsigned long long t = m;
                int k1 = __builtin_ctzll(t); t &= t - 1;
                bool h2 = t != 0; int k2 = h2 ? __builtin_ctzll(t) : k1; t &= t - 1;
                bool h3 = t != 0; int k3 = h3 ? __builtin_ctzll(t) : k1; t &= t - 1;
                bool h4 = t != 0; int k4 = h4 ? __builtin_ctzll(t) : k1;
                int g1 = (w << 6) + k1, g2 = (w << 6) + k2;
                int g3 = (w << 6) + k3, g4 = (w << 6) + k4;
                unsigned short r1 = ROW(g1), r2 = ROW(g2), r3 = ROW(g3), r4 = ROW(g4);
                sup |= r1; if (lane == 0) sel_k[nsel] = (short)g1; nsel++;
                m = ~__ballot((int)((sup >> w) & 1u));
                if (h2 && nsel < MAXOUT && ((m >> k2) & 1ull)) {
                    sup |= r2; if (lane == 0) sel_k[nsel] = (short)g2; nsel++;
                    m = ~__ballot((int)((sup >> w) & 1u));
                }
                if (h3 && nsel < MAXOUT && ((m >> k3) & 1ull)) {
                    sup |= r3; if (lane == 0) sel_k[nsel] = (short)g3; nsel++;
                    m = ~__ballot((int)((sup >> w) & 1u));
                }
                if (h4 && nsel < MAXOUT && ((m >> k4) & 1ull)) {
                    sup |= r4; if (lane == 0) sel_k[nsel] = (short)g4; nsel++;
                    m = ~__ballot((int)((sup >> w) & 1u));
                }
            }
        }
        __builtin_amdgcn_s_waitcnt(0);
        const float* bw = boxes_ws + (size_t)b * 6 * KPAD;
#pragma unroll
        for (int s0 = 0; s0 < 2; ++s0) {
            int s = lane + s0 * 64;
            int valid = s < nsel;
            int k = valid ? (int)sel_k[s] : 0;
            int idx = valid ? order[b * KPAD + k] : 0;
            float vf = valid ? 1.f : 0.f;
            g_idx[b * MAXOUT + s] = idx;
            g_valid[b * MAXOUT + s] = vf;
            float* ob = out_boxes + (size_t)(b * MAXOUT + s) * 6;
#pragma unroll
            for (int c = 0; c < 6; ++c) ob[c] = bw[c * KPAD + k] * vf;
            out_bidx[b * MAXOUT + s] = (float)b;
        }
    }
}

__device__ __forceinline__ void dev_resize(int s, int tid, float* rowbuf,
                                           const float* __restrict__ masks,
                                           const int* __restrict__ g_idx,
                                           const float* __restrict__ g_valid,
                                           float* __restrict__ out_masks) {
    int b = s >> 7;
    int gi = g_idx[s];
    float vf = g_valid[s];
    const float* src = masks + (size_t)(b * NN + gi) * MASK_IN_VOX;
    float* dst = out_masks + (size_t)s * MASK_OUT_VOX;
    int lane = tid & 63;
    float* rb = rowbuf + (tid >> 6) * (64 * 36);
    const float4* s4b = (const float4*)src;

#pragma unroll
    for (int p = 0; p < 4; ++p) {
        int idx = p * 256 + tid;
        int oy = idx & 31, oz = idx >> 5;

        float syf = 0.875f * oy - 0.0625f;
        int fly = (syf >= 0.f) ? (int)syf : -1;
        float fy = syf - (float)fly;
        int y0 = fly < 0 ? 0 : fly;
        int y1 = fly + 1 > 27 ? 27 : fly + 1;

        float szf = 0.875f * oz - 0.0625f;
        int flz = (szf >= 0.f) ? (int)szf : -1;
        float fz = szf - (float)flz;
        int z0 = flz < 0 ? 0 : flz;
        int z1 = flz + 1 > 27 ? 27 : flz + 1;

        float w00 = (1.f - fy) * (1.f - fz);
        float w01 = fy * (1.f - fz);
        float w10 = (1.f - fy) * fz;
        float w11 = fy * fz;

        const float4* r00 = s4b + (z0 * 28 + y0) * 7;
        const float4* r01 = s4b + (z0 * 28 + y1) * 7;
        const float4* r10 = s4b + (z1 * 28 + y0) * 7;
        const float4* r11 = s4b + (z1 * 28 + y1) * 7;

        float c[28];
#pragma unroll
        for (int t = 0; t < 7; ++t) {
            float4 a = r00[t], bb = r01[t], cc = r10[t], dd = r11[t];
            c[4 * t + 0] = a.x * w00 + bb.x * w01 + cc.x * w10 + dd.x * w11;
            c[4 * t + 1] = a.y * w00 + bb.y * w01 + cc.y * w10 + dd.y * w11;
            c[4 * t + 2] = a.z * w00 + bb.z * w01 + cc.z * w10 + dd.z * w11;
            c[4 * t + 3] = a.w * w00 + bb.w * w01 + cc.w * w10 + dd.w * w11;
        }

#pragma unroll
        for (int e = 0; e < 8; ++e) {
            float4 o;
#pragma unroll
            for (int qq = 0; qq < 4; ++qq) {
                const int ox = e * 4 + qq;
                const float sx = 0.875f * (float)ox - 0.0625f;
                const int flx = (ox == 0) ? -1 : (14 * ox - 1) / 16;
                const float fx = sx - (float)flx;
                const int x0 = flx < 0 ? 0 : flx;
                const int x1 = flx + 1 > 27 ? 27 : flx + 1;
                (&o.x)[qq] = (c[x0] + fx * (c[x1] - c[x0])) * vf;
            }
            *(float4*)&rb[lane * 36 + e * 4] = o;
        }

        float4* dchunk = (float4*)dst + (size_t)(p * 256 + (tid & ~63)) * 8;
#pragma unroll
        for (int t = 0; t < 8; ++t) {
            int f = t * 64 + lane;
            float4 v = *(const float4*)&rb[(f >> 3) * 36 + (f & 7) * 4];
            dchunk[f] = v;
        }
    }
}

// ---------------- single dataflow kernel (512 blocks, 2/CU) ------------------
// counters: rank_done[b]=cnt+b*16 (==32), build_done[b]=cnt+64+b*16 (==128),
// walk_done[b]=cnt+128+b*16 (==1). 64 B apart.
__global__ __launch_bounds__(256, 2) void detect_kernel(
        const float* __restrict__ scores, const float* __restrict__ proposals,
        const float* __restrict__ deltas, const float* __restrict__ masks,
        int* __restrict__ order, float* __restrict__ boxes_ws,
        unsigned short* __restrict__ rowBits,
        int* __restrict__ g_idx, float* __restrict__ g_valid,
        float* __restrict__ out_boxes, float* __restrict__ out_masks,
        float* __restrict__ out_bidx,
        uint32_t* __restrict__ cnt) {
    extern __shared__ __align__(16) char smem[];   // 62 KB, aliased by all phases
    int blk = blockIdx.x;
    int tid = threadIdx.x;
    int bb = blk >> 7;                              // batch for build/resize roles

    // P1: rank (blocks 0..127)
    if (blk < 128) {
        dev_rank(blk >> 5, blk & 31, tid, (float*)smem, scores, proposals, deltas,
                 order, boxes_ws);
        arrive(cnt + (blk >> 5) * 16);
    }

    // P2: build (all 512 blocks, 8 rows each)
    wait_for(cnt + bb * 16, 32);
    dev_build(bb, (blk & 127) * 8, tid, (float(*)[1088])smem, boxes_ws, rowBits);
    arrive(cnt + 64 + bb * 16);

    // P3: walk (blocks 0..3)
    if (blk < BB) {
        wait_for(cnt + 64 + blk * 16, 128);
        dev_walk(blk, tid, (unsigned short*)smem, rowBits, order, boxes_ws,
                 out_boxes, out_bidx, g_idx, g_valid);
        arrive(cnt + 128 + blk * 16);
    }

    // P4: resize (block s = blk, one box each)
    wait_for(cnt + 128 + bb * 16, 1);
    dev_resize(blk, tid, (float*)smem, masks, g_idx, g_valid, out_masks);
}

// ---------------- launch ----------------------------------------------------
extern "C" void kernel_launch(void* const* d_in, const int* in_sizes, int n_in,
                              void* d_out, int out_size, void* d_ws, size_t ws_size,
                              hipStream_t stream) {
    const float* proposals = (const float*)d_in[0];
    const float* scores    = (const float*)d_in[1];
    const float* deltas    = (const float*)d_in[2];
    const float* masks     = (const float*)d_in[3];

    float* out = (float*)d_out;
    float* out_boxes = out;                                              // [512,6]
    float* out_masks = out + (size_t)BB * MAXOUT * 6;                    // [512,32768]
    float* out_bidx  = out + (size_t)BB * MAXOUT * 6 + (size_t)BB * MAXOUT * MASK_OUT_VOX;

    char* ws = (char*)d_ws;
    int*            order    = (int*)(ws);                               // 16 KB
    int*            g_idx    = (int*)(ws + (16 << 10));                  // 2 KB
    float*          g_valid  = (float*)(ws + (18 << 10));                // 2 KB
    float*          boxes_ws = (float*)(ws + (20 << 10));                // 96 KB
    unsigned short* rowBits  = (unsigned short*)(ws + (116 << 10));      // 512 KB
    // counters live in rowBits batch-3 pad rows 1000.. (R9-proven never R/W region)
    uint32_t*       cnt      = (uint32_t*)((char*)rowBits
                                           + (size_t)(3 * KPAD + K_PRE) * 64 * 2);

    hipMemsetAsync(cnt, 0, 1024, stream);   // zero counters every call (graph-captured)

    detect_kernel<<<512, 256, DYN_LDS, stream>>>(scores, proposals, deltas, masks,
                                                 order, boxes_ws, rowBits,
                                                 g_idx, g_valid,
                                                 out_boxes, out_masks, out_bidx,
                                                 cnt);
}

// Round 11
// 81.459 us; speedup vs baseline: 1.9195x; 1.0967x over previous
//
#include <hip/hip_runtime.h>
#include <stdint.h>

#define BB 4
#define NN 2000
#define K_PRE 1000
#define KPAD 1024
#define MAXOUT 128
#define NMS_THR 0.3f
#define MASK_IN_VOX (28*28*28)   // 21952
#define MASK_OUT_VOX (32*32*32)  // 32768
#define WALK_LDS (KPAD * 64 * 2) // 128 KB dynamic (attr opt-in; R4-proven)

// ---------------- rank (stable descending argsort) + regression -------------
__global__ __launch_bounds__(256) void rank_kernel(const float* __restrict__ scores,
                                                   const float* __restrict__ proposals,
                                                   const float* __restrict__ deltas,
                                                   int* __restrict__ order,
                                                   float* __restrict__ boxes_ws) {
    int b = blockIdx.x >> 5;
    int blk = blockIdx.x & 31;
    __shared__ float s[NN];
    const float* sb = scores + b * NN;
    for (int u = threadIdx.x; u < NN / 4; u += 256)
        ((float4*)s)[u] = ((const float4*)sb)[u];
    __syncthreads();

    int i = blk * 64 + (threadIdx.x >> 2);
    int q = threadIdx.x & 3;
    float si = (i < NN) ? s[i] : 0.f;
    int cnt = 0;
    int j0 = q * 500;
    const float4* s4 = (const float4*)s;
#pragma unroll 5
    for (int u = 0; u < 125; ++u) {
        float4 v = s4[j0 / 4 + u];
        int j = j0 + u * 4;
        cnt += (v.x > si) + (v.y > si) + (v.z > si) + (v.w > si);
        cnt += ((v.x == si) & (j + 0 < i)) + ((v.y == si) & (j + 1 < i))
             + ((v.z == si) & (j + 2 < i)) + ((v.w == si) & (j + 3 < i));
    }
    cnt += __shfl_xor(cnt, 1);
    cnt += __shfl_xor(cnt, 2);

    if (q == 0 && i < NN && cnt < K_PRE) {
        int rank = cnt;
        order[b * KPAD + rank] = i;
        const float* p = proposals + (size_t)(b * NN + i) * 6;
        const float* d = deltas    + (size_t)(b * NN + i) * 6;
        float py1 = p[0], px1 = p[1], pz1 = p[2], py2 = p[3], px2 = p[4], pz2 = p[5];
        float h = py2 - py1, w = px2 - px1, dd = pz2 - pz1;
        float cy = py1 + 0.5f * h + d[0] * h;
        float cx = px1 + 0.5f * w + d[1] * w;
        float cz = pz1 + 0.5f * dd + d[2] * dd;
        h *= expf(d[3]); w *= expf(d[4]); dd *= expf(d[5]);
        float* bw = boxes_ws + (size_t)b * 6 * KPAD + rank;
        bw[0 * KPAD] = cy - 0.5f * h;  bw[1 * KPAD] = cx - 0.5f * w;  bw[2 * KPAD] = cz - 0.5f * dd;
        bw[3 * KPAD] = cy + 0.5f * h;  bw[4 * KPAD] = cx + 0.5f * w;  bw[5 * KPAD] = cz + 0.5f * dd;
    }
}

// ---------------- suppression bit-matrix build ------------------------------
// rowBits[(b*KPAD+k)*64+l] (uint16): bit w <=> IoU(box k, box 64w+l) > thr
__global__ __launch_bounds__(256) void build_kernel(const float* __restrict__ boxes_ws,
                                                    unsigned short* __restrict__ rowBits) {
    int b = blockIdx.y;
    int kbase = blockIdx.x * 16;
    __shared__ float sbx[6][1088];     // stride-17 padding: index k + (k>>4)
    int tid = threadIdx.x;
    const float* bw = boxes_ws + (size_t)b * 6 * KPAD;
    for (int k = tid; k < KPAD; k += 256) {
        int ks = k + (k >> 4);
#pragma unroll
        for (int c = 0; c < 6; ++c) sbx[c][ks] = bw[c * KPAD + k];
    }
    __syncthreads();
    int l = tid & 63, lr = tid >> 6;
#pragma unroll
    for (int pss = 0; pss < 4; ++pss) {
        int k = kbase + pss * 4 + lr;
        int ks = k + (k >> 4);
        float ry1 = sbx[0][ks], rx1 = sbx[1][ks], rz1 = sbx[2][ks];
        float ry2 = sbx[3][ks], rx2 = sbx[4][ks], rz2 = sbx[5][ks];
        float v1 = (ry2 - ry1) * (rx2 - rx1) * (rz2 - rz1);
        uint32_t bits = 0;
#pragma unroll
        for (int w = 0; w < 16; ++w) {
            int j = 64 * w + l;
            int js = j + (j >> 4);
            float y1 = sbx[0][js], x1 = sbx[1][js], z1 = sbx[2][js];
            float y2 = sbx[3][js], x2 = sbx[4][js], z2 = sbx[5][js];
            float iy = fmaxf(fminf(ry2, y2) - fmaxf(ry1, y1), 0.f);
            float ix = fmaxf(fminf(rx2, x2) - fmaxf(rx1, x1), 0.f);
            float iz = fmaxf(fminf(rz2, z2) - fmaxf(rz1, z1), 0.f);
            float inter = iy * ix * iz;
            float v2 = (y2 - y1) * (x2 - x1) * (z2 - z1);
            float iou = inter / (v1 + v2 - inter + 1e-8f);
            bits |= (iou > NMS_THR ? 1u : 0u) << w;
        }
        if (k < K_PRE)
            rowBits[((size_t)(b * KPAD + k)) * 64 + l] = (unsigned short)bits;
    }
}

// ---------------- ballot walk: full LDS staging + depth-4 prefetch ----------
__global__ __launch_bounds__(256) void walk_kernel(const unsigned short* __restrict__ rowBits,
                                                   const int* __restrict__ order,
                                                   const float* __restrict__ boxes_ws,
                                                   float* __restrict__ out_boxes,
                                                   float* __restrict__ out_bidx,
                                                   int* __restrict__ g_idx,
                                                   float* __restrict__ g_valid) {
    extern __shared__ unsigned short rows_lds[];   // [KPAD][64] = 128 KB
    __shared__ short sel_k[MAXOUT];
    int b = blockIdx.x;
    int tid = threadIdx.x;

    const unsigned short* rowB = rowBits + (size_t)b * KPAD * 64;
    const uint4* src4 = (const uint4*)rowB;
    uint4* dst4 = (uint4*)rows_lds;
    for (int t = tid; t < K_PRE * 64 * 2 / 16; t += 256) dst4[t] = src4[t];
    __syncthreads();
    if (tid < 64) {
        int lane = tid;
        uint32_t sup = (lane >= 40) ? (1u << 15) : 0u;   // pads >=1000 pre-suppressed
        int nsel = 0;

        auto ROW = [&](int g) -> unsigned short { return rows_lds[(g << 6) + lane]; };

        for (int w = 0; w < 16 && nsel < MAXOUT; ++w) {
            unsigned long long m = ~__ballot((int)((sup >> w) & 1u));
            while (m != 0ull && nsel < MAXOUT) {
                unsigned long long t = m;
                int k1 = __builtin_ctzll(t); t &= t - 1;
                bool h2 = t != 0; int k2 = h2 ? __builtin_ctzll(t) : k1; t &= t - 1;
                bool h3 = t != 0; int k3 = h3 ? __builtin_ctzll(t) : k1; t &= t - 1;
                bool h4 = t != 0; int k4 = h4 ? __builtin_ctzll(t) : k1;
                int g1 = (w << 6) + k1, g2 = (w << 6) + k2;
                int g3 = (w << 6) + k3, g4 = (w << 6) + k4;
                unsigned short r1 = ROW(g1), r2 = ROW(g2), r3 = ROW(g3), r4 = ROW(g4);
                sup |= r1; if (lane == 0) sel_k[nsel] = (short)g1; nsel++;
                m = ~__ballot((int)((sup >> w) & 1u));
                if (h2 && nsel < MAXOUT && ((m >> k2) & 1ull)) {
                    sup |= r2; if (lane == 0) sel_k[nsel] = (short)g2; nsel++;
                    m = ~__ballot((int)((sup >> w) & 1u));
                }
                if (h3 && nsel < MAXOUT && ((m >> k3) & 1ull)) {
                    sup |= r3; if (lane == 0) sel_k[nsel] = (short)g3; nsel++;
                    m = ~__ballot((int)((sup >> w) & 1u));
                }
                if (h4 && nsel < MAXOUT && ((m >> k4) & 1ull)) {
                    sup |= r4; if (lane == 0) sel_k[nsel] = (short)g4; nsel++;
                    m = ~__ballot((int)((sup >> w) & 1u));
                }
            }
        }
        __builtin_amdgcn_s_waitcnt(0);  // lane0's LDS writes -> wave-visible
        const float* bw = boxes_ws + (size_t)b * 6 * KPAD;
#pragma unroll
        for (int s0 = 0; s0 < 2; ++s0) {
            int s = lane + s0 * 64;
            int valid = s < nsel;
            int k = valid ? (int)sel_k[s] : 0;
            int idx = valid ? order[b * KPAD + k] : 0;
            float vf = valid ? 1.f : 0.f;
            g_idx[b * MAXOUT + s] = idx;
            g_valid[b * MAXOUT + s] = vf;
            float* ob = out_boxes + (size_t)(b * MAXOUT + s) * 6;
#pragma unroll
            for (int c = 0; c < 6; ++c) ob[c] = bw[c * KPAD + k] * vf;
            out_bidx[b * MAXOUT + s] = (float)b;
        }
    }
}

// ---------------- resize: rolling z-slice LDS staging -----------------------
// Each input slice (28x28 = 3136 B) staged into a 3-slot LDS ring exactly once
// (coalesced float4) -> total HBM read = 87.8 KB/box (minimum). All 8 taps
// read from LDS. Stores: wave = oy 0..7 x ox 0..31 contiguous 1 KB, coalesced.
__global__ __launch_bounds__(256) void resize_kernel(const float* __restrict__ masks,
                                                     const int* __restrict__ g_idx,
                                                     const float* __restrict__ g_valid,
                                                     float* __restrict__ out_masks) {
    int s = blockIdx.x;
    int b = s >> 7;
    int gi = g_idx[s];
    float vf = g_valid[s];
    const float* src = masks + (size_t)(b * NN + gi) * MASK_IN_VOX;
    float* dst = out_masks + (size_t)s * MASK_OUT_VOX;

    __shared__ __align__(16) float ring[3][792];   // 784 + pad
    int tid = threadIdx.x;
    int oy = tid >> 3;
    int ox0 = (tid & 7) * 4;

    // y taps (thread-invariant across oz)
    float syf = 0.875f * oy - 0.0625f;
    int yf = (oy == 0) ? -1 : (14 * oy - 1) >> 4;
    float fy = syf - (float)yf;
    int y0 = yf < 0 ? 0 : yf;
    int y1 = yf + 1 > 27 ? 27 : yf + 1;

    // x taps for this thread's 4 outputs
    int x0a[4], x1a[4];
    float fxa[4];
#pragma unroll
    for (int qq = 0; qq < 4; ++qq) {
        int ox = ox0 + qq;
        int xf = (ox == 0) ? -1 : (14 * ox - 1) >> 4;
        fxa[qq] = (0.875f * ox - 0.0625f) - (float)xf;
        x0a[qq] = xf < 0 ? 0 : xf;
        x1a[qq] = xf + 1 > 27 ? 27 : xf + 1;
    }

    int last = -1;
    for (int oz = 0; oz < 32; ++oz) {
        int zf = (oz == 0) ? -1 : (14 * oz - 1) >> 4;
        float fz = (0.875f * oz - 0.0625f) - (float)zf;
        int z0 = zf < 0 ? 0 : zf;
        int z1 = zf + 1 > 27 ? 27 : zf + 1;

        if (z1 > last) {                        // stage new slice (once per slice)
            __syncthreads();                    // readers of recycled slot done
            if (tid < 196) {
                float4 v = *(const float4*)(src + z1 * 784 + tid * 4);
                *(float4*)&ring[z1 % 3][tid * 4] = v;
            }
            last = z1;
            __syncthreads();
        }

        const float* S0 = ring[z0 % 3];
        const float* S1 = ring[z1 % 3];
        const float* S0y0 = S0 + y0 * 28;
        const float* S0y1 = S0 + y1 * 28;
        const float* S1y0 = S1 + y0 * 28;
        const float* S1y1 = S1 + y1 * 28;

        float4 o;
#pragma unroll
        for (int qq = 0; qq < 4; ++qq) {
            int x0 = x0a[qq], x1 = x1a[qq];
            float fx = fxa[qq];
            float v000 = S0y0[x0], v001 = S0y0[x1];
            float v010 = S0y1[x0], v011 = S0y1[x1];
            float v100 = S1y0[x0], v101 = S1y0[x1];
            float v110 = S1y1[x0], v111 = S1y1[x1];
            float c00 = v000 + fx * (v001 - v000);
            float c01 = v010 + fx * (v011 - v010);
            float c10 = v100 + fx * (v101 - v100);
            float c11 = v110 + fx * (v111 - v110);
            float c0 = c00 + fy * (c01 - c00);
            float c1 = c10 + fy * (c11 - c10);
            (&o.x)[qq] = (c0 + fz * (c1 - c0)) * vf;
        }
        *(float4*)(dst + oz * 1024 + oy * 32 + ox0) = o;
    }
}

// ---------------- launch ----------------------------------------------------
extern "C" void kernel_launch(void* const* d_in, const int* in_sizes, int n_in,
                              void* d_out, int out_size, void* d_ws, size_t ws_size,
                              hipStream_t stream) {
    const float* proposals = (const float*)d_in[0];
    const float* scores    = (const float*)d_in[1];
    const float* deltas    = (const float*)d_in[2];
    const float* masks     = (const float*)d_in[3];

    float* out = (float*)d_out;
    float* out_boxes = out;                                              // [512,6]
    float* out_masks = out + (size_t)BB * MAXOUT * 6;                    // [512,32768]
    float* out_bidx  = out + (size_t)BB * MAXOUT * 6 + (size_t)BB * MAXOUT * MASK_OUT_VOX;

    char* ws = (char*)d_ws;
    int*            order    = (int*)(ws);                               // 16 KB
    int*            g_idx    = (int*)(ws + (16 << 10));                  // 2 KB
    float*          g_valid  = (float*)(ws + (18 << 10));                // 2 KB
    float*          boxes_ws = (float*)(ws + (20 << 10));                // 96 KB
    unsigned short* rowBits  = (unsigned short*)(ws + (116 << 10));      // 512 KB

    static int attr_set = 0;  // host-side, idempotent, capture-safe (R4-proven)
    if (!attr_set) {
        hipFuncSetAttribute(reinterpret_cast<const void*>(walk_kernel),
                            hipFuncAttributeMaxDynamicSharedMemorySize, WALK_LDS);
        attr_set = 1;
    }

    rank_kernel<<<BB * 32, 256, 0, stream>>>(scores, proposals, deltas, order, boxes_ws);
    build_kernel<<<dim3(64, BB), 256, 0, stream>>>(boxes_ws, rowBits);
    walk_kernel<<<BB, 256, WALK_LDS, stream>>>(rowBits, order, boxes_ws,
                                               out_boxes, out_bidx, g_idx, g_valid);
    resize_kernel<<<BB * MAXOUT, 256, 0, stream>>>(masks, g_idx, g_valid, out_masks);
}

// Round 12
// 70.055 us; speedup vs baseline: 2.2319x; 1.1628x over previous
//
#include <hip/hip_runtime.h>
#include <stdint.h>

#define BB 4
#define NN 2000
#define K_PRE 1000
#define KPAD 1024
#define MAXOUT 128
#define NMS_THR 0.3f
#define MASK_IN_VOX (28*28*28)   // 21952
#define MASK_OUT_VOX (32*32*32)  // 32768

// ---------------- rank (stable descending argsort) + regression -------------
__global__ __launch_bounds__(256) void rank_kernel(const float* __restrict__ scores,
                                                   const float* __restrict__ proposals,
                                                   const float* __restrict__ deltas,
                                                   int* __restrict__ order,
                                                   float* __restrict__ boxes_ws) {
    int b = blockIdx.x >> 5;
    int blk = blockIdx.x & 31;
    __shared__ float s[NN];
    const float* sb = scores + b * NN;
    for (int u = threadIdx.x; u < NN / 4; u += 256)
        ((float4*)s)[u] = ((const float4*)sb)[u];
    __syncthreads();

    int i = blk * 64 + (threadIdx.x >> 2);
    int q = threadIdx.x & 3;
    float si = (i < NN) ? s[i] : 0.f;
    int cnt = 0;
    int j0 = q * 500;
    const float4* s4 = (const float4*)s;
#pragma unroll 5
    for (int u = 0; u < 125; ++u) {
        float4 v = s4[j0 / 4 + u];
        int j = j0 + u * 4;
        cnt += (v.x > si) + (v.y > si) + (v.z > si) + (v.w > si);
        cnt += ((v.x == si) & (j + 0 < i)) + ((v.y == si) & (j + 1 < i))
             + ((v.z == si) & (j + 2 < i)) + ((v.w == si) & (j + 3 < i));
    }
    cnt += __shfl_xor(cnt, 1);
    cnt += __shfl_xor(cnt, 2);

    if (q == 0 && i < NN && cnt < K_PRE) {
        int rank = cnt;
        order[b * KPAD + rank] = i;
        const float* p = proposals + (size_t)(b * NN + i) * 6;
        const float* d = deltas    + (size_t)(b * NN + i) * 6;
        float py1 = p[0], px1 = p[1], pz1 = p[2], py2 = p[3], px2 = p[4], pz2 = p[5];
        float h = py2 - py1, w = px2 - px1, dd = pz2 - pz1;
        float cy = py1 + 0.5f * h + d[0] * h;
        float cx = px1 + 0.5f * w + d[1] * w;
        float cz = pz1 + 0.5f * dd + d[2] * dd;
        h *= expf(d[3]); w *= expf(d[4]); dd *= expf(d[5]);
        float* bw = boxes_ws + (size_t)b * 6 * KPAD + rank;
        bw[0 * KPAD] = cy - 0.5f * h;  bw[1 * KPAD] = cx - 0.5f * w;  bw[2 * KPAD] = cz - 0.5f * dd;
        bw[3 * KPAD] = cy + 0.5f * h;  bw[4 * KPAD] = cx + 0.5f * w;  bw[5 * KPAD] = cz + 0.5f * dd;
    }
}

// ---------------- suppression bit-matrix build ------------------------------
// rowBits[(b*KPAD+k)*64+l] (uint16): bit w <=> IoU(box k, box 64w+l) > thr
__global__ __launch_bounds__(256) void build_kernel(const float* __restrict__ boxes_ws,
                                                    unsigned short* __restrict__ rowBits) {
    int b = blockIdx.y;
    int kbase = blockIdx.x * 16;
    __shared__ float sbx[6][1088];     // stride-17 padding: index k + (k>>4)
    int tid = threadIdx.x;
    const float* bw = boxes_ws + (size_t)b * 6 * KPAD;
    for (int k = tid; k < KPAD; k += 256) {
        int ks = k + (k >> 4);
#pragma unroll
        for (int c = 0; c < 6; ++c) sbx[c][ks] = bw[c * KPAD + k];
    }
    __syncthreads();
    int l = tid & 63, lr = tid >> 6;
#pragma unroll
    for (int pss = 0; pss < 4; ++pss) {
        int k = kbase + pss * 4 + lr;
        int ks = k + (k >> 4);
        float ry1 = sbx[0][ks], rx1 = sbx[1][ks], rz1 = sbx[2][ks];
        float ry2 = sbx[3][ks], rx2 = sbx[4][ks], rz2 = sbx[5][ks];
        float v1 = (ry2 - ry1) * (rx2 - rx1) * (rz2 - rz1);
        uint32_t bits = 0;
#pragma unroll
        for (int w = 0; w < 16; ++w) {
            int j = 64 * w + l;
            int js = j + (j >> 4);
            float y1 = sbx[0][js], x1 = sbx[1][js], z1 = sbx[2][js];
            float y2 = sbx[3][js], x2 = sbx[4][js], z2 = sbx[5][js];
            float iy = fmaxf(fminf(ry2, y2) - fmaxf(ry1, y1), 0.f);
            float ix = fmaxf(fminf(rx2, x2) - fmaxf(rx1, x1), 0.f);
            float iz = fmaxf(fminf(rz2, z2) - fmaxf(rz1, z1), 0.f);
            float inter = iy * ix * iz;
            float v2 = (y2 - y1) * (x2 - x1) * (z2 - z1);
            float iou = inter / (v1 + v2 - inter + 1e-8f);
            bits |= (iou > NMS_THR ? 1u : 0u) << w;
        }
        if (k < K_PRE)
            rowBits[((size_t)(b * KPAD + k)) * 64 + l] = (unsigned short)bits;
    }
}

// ---------------- fused walk+resize: block s re-walks to pick #(s&127) ------
// Redundant early-exit ballot walk straight from L2 (rows shared per-XCD),
// then R4-proven row-gather trilinear resize. No walk kernel, no g_idx/g_valid.
__global__ __launch_bounds__(256) void resize_walk_kernel(
        const float* __restrict__ masks,
        const unsigned short* __restrict__ rowBits,
        const int* __restrict__ order,
        const float* __restrict__ boxes_ws,
        float* __restrict__ out_boxes,
        float* __restrict__ out_masks,
        float* __restrict__ out_bidx) {
    int s = blockIdx.x;            // 0..511
    int b = s >> 7;
    int sl = s & 127;              // which pick this block owns
    int tid = threadIdx.x;

    __shared__ int   res_k;
    __shared__ float res_vf;
    __shared__ __align__(16) float rowbuf[4][64 * 36];

    if (tid < 64) {
        int lane = tid;
        const unsigned short* rowB = rowBits + (size_t)b * KPAD * 64;
        uint32_t sup = (lane >= 40) ? (1u << 15) : 0u;   // pads >=1000 pre-suppressed
        int nsel = 0, kmine = 0, got = 0;

        auto ROW = [&](int g) -> unsigned short {
            return rowB[((size_t)g << 6) + lane];        // L2 read, 128 B/row
        };

        for (int w = 0; w < 16 && nsel <= sl; ++w) {
            unsigned long long m = ~__ballot((int)((sup >> w) & 1u));
            while (m != 0ull && nsel <= sl) {
                unsigned long long t = m;
                int k1 = __builtin_ctzll(t); t &= t - 1;
                bool h2 = t != 0; int k2 = h2 ? __builtin_ctzll(t) : k1; t &= t - 1;
                bool h3 = t != 0; int k3 = h3 ? __builtin_ctzll(t) : k1; t &= t - 1;
                bool h4 = t != 0; int k4 = h4 ? __builtin_ctzll(t) : k1;
                int g1 = (w << 6) + k1, g2 = (w << 6) + k2;
                int g3 = (w << 6) + k3, g4 = (w << 6) + k4;
                unsigned short r1 = ROW(g1), r2 = ROW(g2), r3 = ROW(g3), r4 = ROW(g4);
                // pick #nsel is g1 (exact: m is exact)
                if (nsel == sl) { kmine = g1; got = 1; }
                sup |= r1; nsel++;
                m = ~__ballot((int)((sup >> w) & 1u));
                if (h2 && nsel <= sl && ((m >> k2) & 1ull)) {
                    if (nsel == sl) { kmine = g2; got = 1; }
                    sup |= r2; nsel++;
                    m = ~__ballot((int)((sup >> w) & 1u));
                }
                if (h3 && nsel <= sl && ((m >> k3) & 1ull)) {
                    if (nsel == sl) { kmine = g3; got = 1; }
                    sup |= r3; nsel++;
                    m = ~__ballot((int)((sup >> w) & 1u));
                }
                if (h4 && nsel <= sl && ((m >> k4) & 1ull)) {
                    if (nsel == sl) { kmine = g4; got = 1; }
                    sup |= r4; nsel++;
                    m = ~__ballot((int)((sup >> w) & 1u));
                }
            }
        }
        if (lane == 0) { res_k = kmine; res_vf = got ? 1.f : 0.f; }
    }
    __syncthreads();

    int k = res_k;
    float vf = res_vf;
    int gi = order[b * KPAD + k];

    if (tid == 0) {
        const float* bw = boxes_ws + (size_t)b * 6 * KPAD;
        float* ob = out_boxes + (size_t)s * 6;
#pragma unroll
        for (int c = 0; c < 6; ++c) ob[c] = bw[c * KPAD + k] * vf;
        out_bidx[s] = (float)b;
    }

    // ---- R4-proven row-gather trilinear resize ----
    const float* src = masks + (size_t)(b * NN + gi) * MASK_IN_VOX;
    float* dst = out_masks + (size_t)s * MASK_OUT_VOX;
    int lane = tid & 63;
    float* rb = rowbuf[tid >> 6];
    const float4* s4b = (const float4*)src;

#pragma unroll
    for (int p = 0; p < 4; ++p) {
        int idx = p * 256 + tid;
        int oy = idx & 31, oz = idx >> 5;

        float syf = 0.875f * oy - 0.0625f;
        int fly = (syf >= 0.f) ? (int)syf : -1;
        float fy = syf - (float)fly;
        int y0 = fly < 0 ? 0 : fly;
        int y1 = fly + 1 > 27 ? 27 : fly + 1;

        float szf = 0.875f * oz - 0.0625f;
        int flz = (szf >= 0.f) ? (int)szf : -1;
        float fz = szf - (float)flz;
        int z0 = flz < 0 ? 0 : flz;
        int z1 = flz + 1 > 27 ? 27 : flz + 1;

        float w00 = (1.f - fy) * (1.f - fz);
        float w01 = fy * (1.f - fz);
        float w10 = (1.f - fy) * fz;
        float w11 = fy * fz;

        const float4* r00 = s4b + (z0 * 28 + y0) * 7;
        const float4* r01 = s4b + (z0 * 28 + y1) * 7;
        const float4* r10 = s4b + (z1 * 28 + y0) * 7;
        const float4* r11 = s4b + (z1 * 28 + y1) * 7;

        float c[28];
#pragma unroll
        for (int t = 0; t < 7; ++t) {
            float4 a = r00[t], bb = r01[t], cc = r10[t], dd = r11[t];
            c[4 * t + 0] = a.x * w00 + bb.x * w01 + cc.x * w10 + dd.x * w11;
            c[4 * t + 1] = a.y * w00 + bb.y * w01 + cc.y * w10 + dd.y * w11;
            c[4 * t + 2] = a.z * w00 + bb.z * w01 + cc.z * w10 + dd.z * w11;
            c[4 * t + 3] = a.w * w00 + bb.w * w01 + cc.w * w10 + dd.w * w11;
        }

#pragma unroll
        for (int e = 0; e < 8; ++e) {
            float4 o;
#pragma unroll
            for (int qq = 0; qq < 4; ++qq) {
                const int ox = e * 4 + qq;
                const float sx = 0.875f * (float)ox - 0.0625f;
                const int flx = (ox == 0) ? -1 : (14 * ox - 1) / 16;
                const float fx = sx - (float)flx;
                const int x0 = flx < 0 ? 0 : flx;
                const int x1 = flx + 1 > 27 ? 27 : flx + 1;
                (&o.x)[qq] = (c[x0] + fx * (c[x1] - c[x0])) * vf;
            }
            *(float4*)&rb[lane * 36 + e * 4] = o;
        }

        float4* dchunk = (float4*)dst + (size_t)(p * 256 + (tid & ~63)) * 8;
#pragma unroll
        for (int t = 0; t < 8; ++t) {
            int f = t * 64 + lane;
            float4 v = *(const float4*)&rb[(f >> 3) * 36 + (f & 7) * 4];
            dchunk[f] = v;
        }
    }
}

// ---------------- launch ----------------------------------------------------
extern "C" void kernel_launch(void* const* d_in, const int* in_sizes, int n_in,
                              void* d_out, int out_size, void* d_ws, size_t ws_size,
                              hipStream_t stream) {
    const float* proposals = (const float*)d_in[0];
    const float* scores    = (const float*)d_in[1];
    const float* deltas    = (const float*)d_in[2];
    const float* masks     = (const float*)d_in[3];

    float* out = (float*)d_out;
    float* out_boxes = out;                                              // [512,6]
    float* out_masks = out + (size_t)BB * MAXOUT * 6;                    // [512,32768]
    float* out_bidx  = out + (size_t)BB * MAXOUT * 6 + (size_t)BB * MAXOUT * MASK_OUT_VOX;

    char* ws = (char*)d_ws;
    int*            order    = (int*)(ws);                               // 16 KB
    float*          boxes_ws = (float*)(ws + (20 << 10));                // 96 KB
    unsigned short* rowBits  = (unsigned short*)(ws + (116 << 10));      // 512 KB

    rank_kernel<<<BB * 32, 256, 0, stream>>>(scores, proposals, deltas, order, boxes_ws);
    build_kernel<<<dim3(64, BB), 256, 0, stream>>>(boxes_ws, rowBits);
    resize_walk_kernel<<<BB * MAXOUT, 256, 0, stream>>>(masks, rowBits, order, boxes_ws,
                                                        out_boxes, out_masks, out_bidx);
}